// Round 1
// baseline (6988.142 us; speedup 1.0000x reference)
//
#include <hip/hip_runtime.h>
#include <cmath>

// ---------------------------------------------------------------------------
// S2VT: enc LSTM(4096->512) x80, dec LSTM(1024->512) x80, enc-pad x44,
//       dec LSTM x44, plus embedding + output GEMMs.
// Strategy: batch all K-independent input projections as big split-bf16 MFMA
// GEMMs (fp32-grade accuracy via hi/lo decomposition, 3 MFMAs per product);
// run the 248 sequential recurrence steps as small fused fp32 kernels.
// ---------------------------------------------------------------------------

typedef __bf16 bf16x8 __attribute__((ext_vector_type(8)));
typedef float  f32x4  __attribute__((ext_vector_type(4)));

#define LDSROW 40  // bf16 elements per LDS row (32 data + 4 pad -> 80B stride)

// C[M,N] = A[M,K] @ Bw[N,K]^T  (+ bias[n])  (+ C_old if ACCUM)
// A, Bw fp32 row-major with leading dims lda/ldb. M must be a multiple of 128.
template<bool BIAS, bool ACCUM>
__global__ __launch_bounds__(256)
void gemm_split(const float* __restrict__ A, int lda,
                const float* __restrict__ Bw, int ldb,
                float* __restrict__ C, int ldc,
                const float* __restrict__ bias,
                int M, int N, int K)
{
    (void)M;
    __shared__ __bf16 sAh[128 * LDSROW], sAl[128 * LDSROW];
    __shared__ __bf16 sBh[128 * LDSROW], sBl[128 * LDSROW];

    const int tid  = threadIdx.x;
    const int lane = tid & 63;
    const int wid  = tid >> 6;
    const int m0 = blockIdx.x * 128, n0 = blockIdx.y * 128;
    const int wm = (wid >> 1) * 64, wn = (wid & 1) * 64;
    const int lr = lane & 15, lg = lane >> 4;

    const int srow = tid >> 1;             // 0..127
    const int scol = (tid & 1) * 16;       // 0 or 16

    f32x4 acc[4][4];
#pragma unroll
    for (int mt = 0; mt < 4; ++mt)
#pragma unroll
        for (int nt = 0; nt < 4; ++nt) acc[mt][nt] = (f32x4)(0.0f);

    const int KT = (K + 31) >> 5;
    for (int kt = 0; kt < KT; ++kt) {
        const int k0 = kt * 32;
        // ---- stage A tile (fp32 -> bf16 hi/lo) ----
        {
            const float* aptr = A + (size_t)(m0 + srow) * lda + k0 + scol;
            float x[16];
            if (k0 + scol + 16 <= K) {
                const f32x4* p = (const f32x4*)aptr;
                f32x4 v0 = p[0], v1 = p[1], v2 = p[2], v3 = p[3];
#pragma unroll
                for (int j = 0; j < 4; ++j) { x[j] = v0[j]; x[4+j] = v1[j]; x[8+j] = v2[j]; x[12+j] = v3[j]; }
            } else {
#pragma unroll
                for (int j = 0; j < 16; ++j) {
                    const int kk = k0 + scol + j;
                    x[j] = (kk < K) ? aptr[j] : 0.f;
                }
            }
#pragma unroll
            for (int j = 0; j < 16; ++j) {
                const float v = x[j];
                const __bf16 h = (__bf16)v;
                sAh[srow * LDSROW + scol + j] = h;
                sAl[srow * LDSROW + scol + j] = (__bf16)(v - (float)h);
            }
        }
        // ---- stage B tile ----
        {
            const int nrow = n0 + srow;
            const float* bptr = Bw + (size_t)nrow * ldb + k0 + scol;
            float x[16];
            if (nrow < N && k0 + scol + 16 <= K) {
                const f32x4* p = (const f32x4*)bptr;
                f32x4 v0 = p[0], v1 = p[1], v2 = p[2], v3 = p[3];
#pragma unroll
                for (int j = 0; j < 4; ++j) { x[j] = v0[j]; x[4+j] = v1[j]; x[8+j] = v2[j]; x[12+j] = v3[j]; }
            } else {
#pragma unroll
                for (int j = 0; j < 16; ++j) {
                    const int kk = k0 + scol + j;
                    x[j] = (nrow < N && kk < K) ? bptr[j] : 0.f;
                }
            }
#pragma unroll
            for (int j = 0; j < 16; ++j) {
                const float v = x[j];
                const __bf16 h = (__bf16)v;
                sBh[srow * LDSROW + scol + j] = h;
                sBl[srow * LDSROW + scol + j] = (__bf16)(v - (float)h);
            }
        }
        __syncthreads();

        bf16x8 ah[4], al[4], bh[4], bl[4];
#pragma unroll
        for (int t = 0; t < 4; ++t) {
            ah[t] = *(const bf16x8*)&sAh[(wm + t * 16 + lr) * LDSROW + lg * 8];
            al[t] = *(const bf16x8*)&sAl[(wm + t * 16 + lr) * LDSROW + lg * 8];
            bh[t] = *(const bf16x8*)&sBh[(wn + t * 16 + lr) * LDSROW + lg * 8];
            bl[t] = *(const bf16x8*)&sBl[(wn + t * 16 + lr) * LDSROW + lg * 8];
        }
#pragma unroll
        for (int mt = 0; mt < 4; ++mt)
#pragma unroll
            for (int nt = 0; nt < 4; ++nt) {
                f32x4 a_ = acc[mt][nt];
                a_ = __builtin_amdgcn_mfma_f32_16x16x32_bf16(ah[mt], bh[nt], a_, 0, 0, 0);
                a_ = __builtin_amdgcn_mfma_f32_16x16x32_bf16(ah[mt], bl[nt], a_, 0, 0, 0);
                a_ = __builtin_amdgcn_mfma_f32_16x16x32_bf16(al[mt], bh[nt], a_, 0, 0, 0);
                acc[mt][nt] = a_;
            }
        __syncthreads();
    }

    // epilogue: D row = 4*(lane>>4)+r (M), col = lane&15 (N)
#pragma unroll
    for (int mt = 0; mt < 4; ++mt)
#pragma unroll
        for (int nt = 0; nt < 4; ++nt)
#pragma unroll
            for (int r = 0; r < 4; ++r) {
                const int m = m0 + wm + mt * 16 + lg * 4 + r;
                const int n = n0 + wn + nt * 16 + lr;
                if (n < N) {
                    float v = acc[mt][nt][r];
                    if (BIAS) v += bias[n];
                    if (ACCUM) v += C[(size_t)m * ldc + n];
                    C[(size_t)m * ldc + n] = v;
                }
            }
}

// ---------------------------------------------------------------------------
// One LSTM step: gates = gpre(+bias) + h_prev @ Whh^T ; pointwise update.
// grid (32, 8): blockIdx.x -> 16 hidden units, blockIdx.y -> 16 batch rows.
// Thread (jj,bb) computes all 4 gates of (b, j) in fp32.
// ---------------------------------------------------------------------------
__global__ __launch_bounds__(256)
void lstm_step(const float* __restrict__ gpre,   // [128][2048] or null
               const float* __restrict__ bias,   // [2048] or null
               const float* __restrict__ Whh,    // [2048][512]
               const float* __restrict__ h_prev, // [128][512]
               float* __restrict__ c,            // [128][512] in/out
               float* __restrict__ h_out)        // [128][512]
{
    __shared__ float h_s[16][36];
    __shared__ float w_s[64][36];
    const int tid = threadIdx.x;
    const int jj = tid & 15, bb = tid >> 4;
    const int j = blockIdx.x * 16 + jj;
    const int b = blockIdx.y * 16 + bb;

    float a0 = 0.f, a1 = 0.f, a2 = 0.f, a3 = 0.f;

    const int hr = tid >> 4, hc = (tid & 15) * 2;      // h stage: 16x32 via float2
    const int wr = tid >> 2, wc = (tid & 3) * 8;       // W stage: 64x32 via 2x float4
    const int wg = wr >> 4, wj = wr & 15;
    const float* hsrc = h_prev + (size_t)(blockIdx.y * 16 + hr) * 512 + hc;
    const float* wsrc = Whh + (size_t)(wg * 512 + blockIdx.x * 16 + wj) * 512 + wc;

    for (int kt = 0; kt < 16; ++kt) {
        const int k0 = kt * 32;
        {
            const float2 hv = *(const float2*)(hsrc + k0);
            h_s[hr][hc] = hv.x; h_s[hr][hc + 1] = hv.y;
            const f32x4 w0 = *(const f32x4*)(wsrc + k0);
            const f32x4 w1 = *(const f32x4*)(wsrc + k0 + 4);
#pragma unroll
            for (int q = 0; q < 4; ++q) { w_s[wr][wc + q] = w0[q]; w_s[wr][wc + 4 + q] = w1[q]; }
        }
        __syncthreads();
#pragma unroll
        for (int k = 0; k < 32; ++k) {
            const float hvk = h_s[bb][k];
            a0 += hvk * w_s[ 0 + jj][k];
            a1 += hvk * w_s[16 + jj][k];
            a2 += hvk * w_s[32 + jj][k];
            a3 += hvk * w_s[48 + jj][k];
        }
        __syncthreads();
    }

    float pi = 0.f, pf = 0.f, pg = 0.f, po = 0.f;
    if (gpre) {
        const float* g = gpre + (size_t)b * 2048 + j;
        pi = g[0]; pf = g[512]; pg = g[1024]; po = g[1536];
    }
    if (bias) { pi += bias[j]; pf += bias[j + 512]; pg += bias[j + 1024]; po += bias[j + 1536]; }
    pi += a0; pf += a1; pg += a2; po += a3;

    const float ig = 1.f / (1.f + __expf(-pi));
    const float fg = 1.f / (1.f + __expf(-pf));
    const float gg = tanhf(pg);
    const float og = 1.f / (1.f + __expf(-po));

    const size_t ci = (size_t)b * 512 + j;
    const float cn = fg * c[ci] + ig * gg;
    c[ci] = cn;
    h_out[ci] = og * tanhf(cn);
}

__global__ void add2(const float* __restrict__ a, const float* __restrict__ b,
                     float* __restrict__ o, int n)
{
    const int i = blockIdx.x * 256 + threadIdx.x;
    if (i < n) o[i] = a[i] + b[i];
}

// emb[0:128, 0:512] = Wi[d][2998] + bi[d]   (<BOS> one-hot embedding)
__global__ void emb_bos(const float* __restrict__ Wi, const float* __restrict__ bi,
                        float* __restrict__ emb)
{
    const int i = blockIdx.x * 256 + threadIdx.x;  // 0..65535 = b*512+d
    const int d = i & 511;
    emb[i] = Wi[(size_t)d * 3000 + 2998] + bi[d];
}

extern "C" void kernel_launch(void* const* d_in, const int* in_sizes, int n_in,
                              void* d_out, int out_size, void* d_ws, size_t ws_size,
                              hipStream_t stream)
{
    (void)in_sizes; (void)n_in; (void)out_size; (void)ws_size;
    const float* in_feat = (const float*)d_in[0];   // (128,80,4096) == flat (10240,4096)
    const float* ca      = (const float*)d_in[1];   // (44,128,3000)
    const float* We_ih   = (const float*)d_in[2];   // (2048,4096)
    const float* We_hh   = (const float*)d_in[3];   // (2048,512)
    const float* be_ih   = (const float*)d_in[4];
    const float* be_hh   = (const float*)d_in[5];
    const float* Wd_ih   = (const float*)d_in[6];   // (2048,1024)
    const float* Wd_hh   = (const float*)d_in[7];   // (2048,512)
    const float* bd_ih   = (const float*)d_in[8];
    const float* bd_hh   = (const float*)d_in[9];
    const float* Wi      = (const float*)d_in[10];  // (512,3000)
    const float* bi      = (const float*)d_in[11];  // (512)
    const float* Wo      = (const float*)d_in[12];  // (3000,512)
    const float* bo      = (const float*)d_in[13];  // (3000)
    float* out = (float*)d_out;                      // (44,128,3000)
    float* ws  = (float*)d_ws;

    // workspace layout (floats); total ~141.3 MB
    float* be    = ws;                       // 2048
    float* bd    = be + 2048;                // 2048
    float* Xbuf  = bd + 2048;                // 10240*2048 (reused for all gate-preacts)
    float* encH  = Xbuf + (size_t)10240 * 2048;   // 81 slots of 128*512
    float* padH  = encH + (size_t)81 * 65536;     // 45 slots
    float* doutH = padH + (size_t)45 * 65536;     // 45 slots
    float* emb   = doutH + (size_t)45 * 65536;    // 5632*512
    float* cE    = emb + (size_t)5632 * 512;      // 128*512
    float* cD    = cE + 65536;
    float* hd0   = cD + 65536;
    float* hd1   = hd0 + 65536;

    // combined biases
    add2<<<dim3(8), dim3(256), 0, stream>>>(be_ih, be_hh, be, 2048);
    add2<<<dim3(8), dim3(256), 0, stream>>>(bd_ih, bd_hh, bd, 2048);

    // zero initial states
    hipMemsetAsync(encH, 0, 65536 * sizeof(float), stream);  // enc h0
    hipMemsetAsync(cE,   0, 65536 * sizeof(float), stream);
    hipMemsetAsync(cD,   0, 65536 * sizeof(float), stream);
    hipMemsetAsync(hd0,  0, 65536 * sizeof(float), stream);  // dec h0

    // <BOS> embedding row
    emb_bos<<<dim3(256), dim3(256), 0, stream>>>(Wi, bi, emb);

    // G1: encoder input projection for all 80 steps
    gemm_split<true, false><<<dim3(80, 16), dim3(256), 0, stream>>>(
        in_feat, 4096, We_ih, 4096, Xbuf, 2048, be, 10240, 2048, 4096);

    // embedding GEMM: correct_answer[1:44] @ Wi^T + bi  -> emb rows 128..5631
    gemm_split<true, false><<<dim3(43, 4), dim3(256), 0, stream>>>(
        ca + (size_t)128 * 3000, 3000, Wi, 3000, emb + (size_t)128 * 512, 512, bi,
        5504, 512, 3000);

    // encoder recurrence (80 steps), h history -> encH slots 1..80
    for (int t = 0; t < 80; ++t)
        lstm_step<<<dim3(32, 8), dim3(256), 0, stream>>>(
            Xbuf + (size_t)t * 262144, nullptr, We_hh,
            encH + (size_t)t * 65536, cE, encH + (size_t)(t + 1) * 65536);

    // decoder phase-1 input projection (input = [enc_seq, zeros])
    gemm_split<true, false><<<dim3(80, 16), dim3(256), 0, stream>>>(
        encH + 65536, 512, Wd_ih, 1024, Xbuf, 2048, bd, 10240, 2048, 512);

    // decoder phase-1 recurrence (outputs discarded; keeps hd, cd)
    for (int t = 0; t < 80; ++t) {
        float* hin  = (t & 1) ? hd1 : hd0;
        float* hout = (t & 1) ? hd0 : hd1;
        lstm_step<<<dim3(32, 8), dim3(256), 0, stream>>>(
            Xbuf + (size_t)t * 262144, nullptr, Wd_hh, hin, cD, hout);
    }
    // 80 steps (even) -> final hd lives in hd0

    // encoder over zero padding (44 steps) from (he, ce); h -> padH slots 1..44
    for (int t = 0; t < 44; ++t) {
        const float* hin = (t == 0) ? (encH + (size_t)80 * 65536) : (padH + (size_t)t * 65536);
        lstm_step<<<dim3(32, 8), dim3(256), 0, stream>>>(
            nullptr, be, We_hh, hin, cE, padH + (size_t)(t + 1) * 65536);
    }

    // decoder phase-2 input projection: emb @ Wd_ih[:,:512]^T + enc_pad @ Wd_ih[:,512:]^T + bd
    gemm_split<true, false><<<dim3(44, 16), dim3(256), 0, stream>>>(
        emb, 512, Wd_ih, 1024, Xbuf, 2048, bd, 5632, 2048, 512);
    gemm_split<false, true><<<dim3(44, 16), dim3(256), 0, stream>>>(
        padH + 65536, 512, Wd_ih + 512, 1024, Xbuf, 2048, nullptr, 5632, 2048, 512);

    // decoder phase-2 recurrence from (hd, cd); h -> doutH slots 1..44
    for (int t = 0; t < 44; ++t) {
        const float* hin = (t == 0) ? hd0 : (doutH + (size_t)t * 65536);
        lstm_step<<<dim3(32, 8), dim3(256), 0, stream>>>(
            Xbuf + (size_t)t * 262144, nullptr, Wd_hh, hin, cD, doutH + (size_t)(t + 1) * 65536);
    }

    // words = dec_out @ Wo^T + bo
    gemm_split<true, false><<<dim3(44, 24), dim3(256), 0, stream>>>(
        doutH + 65536, 512, Wo, 512, out, 3000, bo, 5632, 3000, 512);
}